// Round 5
// baseline (369.169 us; speedup 1.0000x reference)
//
#include <hip/hip_runtime.h>

#define T 2048
#define DIM 1024
#define NE 8
#define ED 2048
#define NSLOT (T * 2)
#define KSPLIT 2
#define WTOT (NE * ED * DIM)        // elements per weight tensor (16M)
#define NCHUNK (WTOT / 8)           // 2M 8-elem chunks per tensor
#define CONVB 2048                  // convert blocks (4 chunks/thread)
#define CONVSTRIDE (CONVB * 256)    // 524288 threads

#define BM 128
#define BN 128
#define BK 64
#define MAXWL 40

typedef __attribute__((ext_vector_type(8))) short s8v;   // 8 bf16 = 4 VGPRs
typedef __attribute__((ext_vector_type(4))) float f32x4; // MFMA C/D

__device__ __forceinline__ short f2bf(float f) {
    union { float f; unsigned u; } v;
    v.f = f;
    unsigned r = 0x7FFFu + ((v.u >> 16) & 1u);  // round-to-nearest-even
    v.u += r;
    return (short)(v.u >> 16);
}

__device__ __forceinline__ float bf2f(short s) {
    union { unsigned u; float f; } v;
    v.u = ((unsigned)(unsigned short)s) << 16;
    return v.f;
}

// async global->LDS, 16B per lane; lds dst wave-uniform base, lane i -> base+16i
__device__ __forceinline__ void glds16(const void* g, void* l) {
    __builtin_amdgcn_global_load_lds(
        (const __attribute__((address_space(1))) void*)g,
        (__attribute__((address_space(3))) void*)l, 16, 0, 0);
}

// ---------------- prep: weight fp32->bf16 convert (4 chunks/thread) + router ----------------
__global__ __launch_bounds__(256) void prep_kernel(
    const float* __restrict__ w1, const float* __restrict__ w2,
    short* __restrict__ w1b, short* __restrict__ w2b,
    const float* __restrict__ x, const float* __restrict__ gw,
    const float* __restrict__ bias, short* __restrict__ xb,
    int* __restrict__ counts, int* __restrict__ top2i, float* __restrict__ top2w) {
    int bx = blockIdx.x;
    if (bx < CONVB) {
        size_t t0 = (size_t)bx * 256 + threadIdx.x;
        float4 v1[8], v2[8];
        // issue all 16 loads before converting/storing: 1KB/lane in flight
#pragma unroll
        for (int j = 0; j < 4; ++j) {
            const float* p1 = w1 + (t0 + (size_t)j * CONVSTRIDE) * 8;
            v1[j * 2 + 0] = *(const float4*)(p1);
            v1[j * 2 + 1] = *(const float4*)(p1 + 4);
        }
#pragma unroll
        for (int j = 0; j < 4; ++j) {
            const float* p2 = w2 + (t0 + (size_t)j * CONVSTRIDE) * 8;
            v2[j * 2 + 0] = *(const float4*)(p2);
            v2[j * 2 + 1] = *(const float4*)(p2 + 4);
        }
#pragma unroll
        for (int j = 0; j < 4; ++j) {
            float4 a0 = v1[j * 2], a1 = v1[j * 2 + 1];
            s8v o1 = { f2bf(a0.x), f2bf(a0.y), f2bf(a0.z), f2bf(a0.w),
                       f2bf(a1.x), f2bf(a1.y), f2bf(a1.z), f2bf(a1.w) };
            *(s8v*)(w1b + (t0 + (size_t)j * CONVSTRIDE) * 8) = o1;
        }
#pragma unroll
        for (int j = 0; j < 4; ++j) {
            float4 b0 = v2[j * 2], b1 = v2[j * 2 + 1];
            s8v o2 = { f2bf(b0.x), f2bf(b0.y), f2bf(b0.z), f2bf(b0.w),
                       f2bf(b1.x), f2bf(b1.y), f2bf(b1.z), f2bf(b1.w) };
            *(s8v*)(w2b + (t0 + (size_t)j * CONVSTRIDE) * 8) = o2;
        }
        return;
    }
    // router: 1 wave per token
    int wid = threadIdx.x >> 6;
    int lane = threadIdx.x & 63;
    int t = (bx - CONVB) * 4 + wid;

    const float* xr = x + (size_t)t * DIM + lane * 16;
    float4 xv[4];
#pragma unroll
    for (int j = 0; j < 4; ++j) xv[j] = *(const float4*)(xr + j * 4);

    s8v o0, o1;
#pragma unroll
    for (int j = 0; j < 2; ++j) {
        o0[j * 4 + 0] = f2bf(xv[j].x); o0[j * 4 + 1] = f2bf(xv[j].y);
        o0[j * 4 + 2] = f2bf(xv[j].z); o0[j * 4 + 3] = f2bf(xv[j].w);
        o1[j * 4 + 0] = f2bf(xv[j + 2].x); o1[j * 4 + 1] = f2bf(xv[j + 2].y);
        o1[j * 4 + 2] = f2bf(xv[j + 2].z); o1[j * 4 + 3] = f2bf(xv[j + 2].w);
    }
    *(s8v*)(xb + (size_t)t * DIM + lane * 16) = o0;
    *(s8v*)(xb + (size_t)t * DIM + lane * 16 + 8) = o1;

    float sc[NE];
#pragma unroll
    for (int e = 0; e < NE; ++e) {
        const float* gr = gw + e * DIM + lane * 16;
        float p = 0.f;
#pragma unroll
        for (int j = 0; j < 4; ++j) {
            float4 g = *(const float4*)(gr + j * 4);
            p += xv[j].x * g.x + xv[j].y * g.y + xv[j].z * g.z + xv[j].w * g.w;
        }
#pragma unroll
        for (int off = 32; off; off >>= 1) p += __shfl_xor(p, off, 64);
        sc[e] = 1.f / (1.f + __expf(-(p + bias[e])));
    }
    int b0 = 0; float s0 = sc[0];
#pragma unroll
    for (int e = 1; e < NE; ++e) if (sc[e] > s0) { s0 = sc[e]; b0 = e; }
    int b1 = -1; float s1 = -1e30f;
#pragma unroll
    for (int e = 0; e < NE; ++e) if (e != b0 && sc[e] > s1) { s1 = sc[e]; b1 = e; }
    float inv = 1.f / (s0 + s1 + 1e-6f);
    if (lane == 0) {
        top2i[t * 2 + 0] = b0; top2i[t * 2 + 1] = b1;
        top2w[t * 2 + 0] = s0 * inv; top2w[t * 2 + 1] = s1 * inv;
        atomicAdd(&counts[b0], 1);
        atomicAdd(&counts[b1], 1);
    }
}

// ---------------- plan: prefix + worklist + scatter ----------------
__global__ __launch_bounds__(256) void plan_kernel(
    const int* __restrict__ counts, const int* __restrict__ top2i,
    int* __restrict__ offsets, int* __restrict__ tok_list, int* __restrict__ slot_of,
    int* __restrict__ wl, int* __restrict__ nwl) {
    __shared__ int soff[NE];
    __shared__ int srun[NE];
    if (threadIdx.x == 0) {
        int a = 0;
        for (int e = 0; e < NE; ++e) { soff[e] = a; offsets[e] = a; a += counts[e]; srun[e] = 0; }
        int n = 0;
        for (int e = 0; e < NE; ++e) {
            int mt = (counts[e] + BM - 1) / BM;
            for (int m = 0; m < mt; ++m) wl[n++] = (e << 16) | m;
        }
        *nwl = n;
    }
    __syncthreads();
    for (int t = threadIdx.x; t < T; t += 256) {
#pragma unroll
        for (int k = 0; k < 2; ++k) {
            int e = top2i[t * 2 + k];
            int pos = atomicAdd(&srun[e], 1);
            int slot = soff[e] + pos;
            tok_list[slot] = t;
            slot_of[t * 2 + k] = slot;
        }
    }
}

// ---------------- grouped GEMM1: h = silu(x @ w1^T), BK=64 dbuf one-barrier ----------------
__global__ __launch_bounds__(256) void ffn1_kernel(
    const short* __restrict__ xb, const short* __restrict__ w1b,
    const int* __restrict__ counts, const int* __restrict__ offsets,
    const int* __restrict__ tok_list, const int* __restrict__ wl,
    const int* __restrict__ nwl, short* __restrict__ h) {
    int my = blockIdx.y;
    if (my >= *nwl) return;
    int e = wl[my] >> 16;
    int m0 = (wl[my] & 0xffff) * BM;
    int cnt = counts[e];
    int off = offsets[e];
    int n0 = blockIdx.x * BN;

    __shared__ __align__(16) short As[2][8][BM][8];   // 2 x 16 KiB
    __shared__ __align__(16) short Bs[2][8][BN][8];   // 2 x 16 KiB

    int tid = threadIdx.x;
    int lane = tid & 63, w = tid >> 6;
    int mo = (w >> 1) * 64, no = (w & 1) * 64;
    int lrow = lane & 15, lq = lane >> 4;

    f32x4 acc[4][4];
#pragma unroll
    for (int mi = 0; mi < 4; ++mi)
#pragma unroll
        for (int ni = 0; ni < 4; ++ni) acc[mi][ni] = (f32x4){0.f, 0.f, 0.f, 0.f};

    int ra0 = m0 + lane;      if (ra0 > cnt - 1) ra0 = cnt - 1;
    int ra1 = m0 + 64 + lane; if (ra1 > cnt - 1) ra1 = cnt - 1;
    // per-lane global sources (glds global addr is per-lane; LDS dst is uniform+lane*16)
    const short* a0 = xb + (size_t)tok_list[off + ra0] * DIM + 2 * w * 8;   // kq = 2w
    const short* a1 = xb + (size_t)tok_list[off + ra1] * DIM + 2 * w * 8;
    const short* b0 = w1b + ((size_t)e * ED + n0 + lane) * DIM + 2 * w * 8;
    const short* b1 = b0 + (size_t)64 * DIM;

    const int NK = DIM / BK;       // 16
#define STAGE1(buf, k0)                                                        \
    do {                                                                       \
        glds16(a0 + (k0),     &As[buf][2 * w][0][0]);                          \
        glds16(a1 + (k0),     &As[buf][2 * w][64][0]);                         \
        glds16(a0 + (k0) + 8, &As[buf][2 * w + 1][0][0]);                      \
        glds16(a1 + (k0) + 8, &As[buf][2 * w + 1][64][0]);                     \
        glds16(b0 + (k0),     &Bs[buf][2 * w][0][0]);                          \
        glds16(b1 + (k0),     &Bs[buf][2 * w][64][0]);                         \
        glds16(b0 + (k0) + 8, &Bs[buf][2 * w + 1][0][0]);                      \
        glds16(b1 + (k0) + 8, &Bs[buf][2 * w + 1][64][0]);                     \
    } while (0)

    STAGE1(0, 0);
    for (int kk = 0; kk < NK; ++kk) {
        int cur = kk & 1;
        __syncthreads();   // drains glds issued LAST iter (had full compute phase)
        if (kk + 1 < NK) STAGE1(cur ^ 1, (kk + 1) * BK);
#pragma unroll
        for (int ks = 0; ks < 2; ++ks) {
            s8v af[4], bf[4];
#pragma unroll
            for (int mi = 0; mi < 4; ++mi) af[mi] = *(const s8v*)&As[cur][ks * 4 + lq][mo + mi * 16 + lrow][0];
#pragma unroll
            for (int ni = 0; ni < 4; ++ni) bf[ni] = *(const s8v*)&Bs[cur][ks * 4 + lq][no + ni * 16 + lrow][0];
#pragma unroll
            for (int mi = 0; mi < 4; ++mi)
#pragma unroll
                for (int ni = 0; ni < 4; ++ni)
                    acc[mi][ni] = __builtin_amdgcn_mfma_f32_16x16x32_bf16(af[mi], bf[ni], acc[mi][ni], 0, 0, 0);
        }
    }
#undef STAGE1

#pragma unroll
    for (int mi = 0; mi < 4; ++mi) {
#pragma unroll
        for (int ni = 0; ni < 4; ++ni) {
            int ln = n0 + no + ni * 16 + lrow;
#pragma unroll
            for (int r = 0; r < 4; ++r) {
                int row = m0 + mo + mi * 16 + lq * 4 + r;
                if (row < cnt) {
                    float v = acc[mi][ni][r];
                    v = v / (1.f + __expf(-v));  // silu
                    h[(size_t)(off + row) * ED + ln] = f2bf(v);
                }
            }
        }
    }
}

// ---------------- grouped GEMM2 (K-split, BK=64 dbuf): eo[ks][slot] = h @ w2^T[kchunk] ----------------
__global__ __launch_bounds__(256) void ffn2_kernel(
    const short* __restrict__ h, const short* __restrict__ w2b,
    const int* __restrict__ counts, const int* __restrict__ offsets,
    const int* __restrict__ wl, const int* __restrict__ nwl,
    short* __restrict__ eo) {
    int my = blockIdx.y;
    if (my >= *nwl) return;
    int e = wl[my] >> 16;
    int m0 = (wl[my] & 0xffff) * BM;
    int ksp = blockIdx.z;
    int cnt = counts[e];
    int off = offsets[e];
    int n0 = blockIdx.x * BN;
    const int kbase = ksp * (ED / KSPLIT);

    __shared__ __align__(16) short As[2][8][BM][8];
    __shared__ __align__(16) short Bs[2][8][BN][8];

    int tid = threadIdx.x;
    int lane = tid & 63, w = tid >> 6;
    int mo = (w >> 1) * 64, no = (w & 1) * 64;
    int lrow = lane & 15, lq = lane >> 4;

    f32x4 acc[4][4];
#pragma unroll
    for (int mi = 0; mi < 4; ++mi)
#pragma unroll
        for (int ni = 0; ni < 4; ++ni) acc[mi][ni] = (f32x4){0.f, 0.f, 0.f, 0.f};

    int ra0 = m0 + lane;      if (ra0 > cnt - 1) ra0 = cnt - 1;
    int ra1 = m0 + 64 + lane; if (ra1 > cnt - 1) ra1 = cnt - 1;
    const short* a0 = h + (size_t)(off + ra0) * ED + kbase + 2 * w * 8;
    const short* a1 = h + (size_t)(off + ra1) * ED + kbase + 2 * w * 8;
    const short* b0 = w2b + ((size_t)e * DIM + n0 + lane) * ED + kbase + 2 * w * 8;
    const short* b1 = b0 + (size_t)64 * ED;

    const int NK = (ED / KSPLIT) / BK;   // 16
#define STAGE2(buf, k0)                                                        \
    do {                                                                       \
        glds16(a0 + (k0),     &As[buf][2 * w][0][0]);                          \
        glds16(a1 + (k0),     &As[buf][2 * w][64][0]);                         \
        glds16(a0 + (k0) + 8, &As[buf][2 * w + 1][0][0]);                      \
        glds16(a1 + (k0) + 8, &As[buf][2 * w + 1][64][0]);                     \
        glds16(b0 + (k0),     &Bs[buf][2 * w][0][0]);                          \
        glds16(b1 + (k0),     &Bs[buf][2 * w][64][0]);                         \
        glds16(b0 + (k0) + 8, &Bs[buf][2 * w + 1][0][0]);                      \
        glds16(b1 + (k0) + 8, &Bs[buf][2 * w + 1][64][0]);                     \
    } while (0)

    STAGE2(0, 0);
    for (int kk = 0; kk < NK; ++kk) {
        int cur = kk & 1;
        __syncthreads();
        if (kk + 1 < NK) STAGE2(cur ^ 1, (kk + 1) * BK);
#pragma unroll
        for (int ks = 0; ks < 2; ++ks) {
            s8v af[4], bf[4];
#pragma unroll
            for (int mi = 0; mi < 4; ++mi) af[mi] = *(const s8v*)&As[cur][ks * 4 + lq][mo + mi * 16 + lrow][0];
#pragma unroll
            for (int ni = 0; ni < 4; ++ni) bf[ni] = *(const s8v*)&Bs[cur][ks * 4 + lq][no + ni * 16 + lrow][0];
#pragma unroll
            for (int mi = 0; mi < 4; ++mi)
#pragma unroll
                for (int ni = 0; ni < 4; ++ni)
                    acc[mi][ni] = __builtin_amdgcn_mfma_f32_16x16x32_bf16(af[mi], bf[ni], acc[mi][ni], 0, 0, 0);
        }
    }
#undef STAGE2

    short* eop = eo + (size_t)ksp * NSLOT * DIM;
#pragma unroll
    for (int mi = 0; mi < 4; ++mi) {
#pragma unroll
        for (int ni = 0; ni < 4; ++ni) {
            int ln = n0 + no + ni * 16 + lrow;
#pragma unroll
            for (int r = 0; r < 4; ++r) {
                int row = m0 + mo + mi * 16 + lq * 4 + r;
                if (row < cnt) {
                    eop[(size_t)(off + row) * DIM + ln] = f2bf(acc[mi][ni][r]);
                }
            }
        }
    }
}

// ---------------- combine ----------------
__global__ __launch_bounds__(256) void combine_kernel(
    const short* __restrict__ eo, const int* __restrict__ slot_of,
    const float* __restrict__ top2w, float* __restrict__ out) {
    int idx = blockIdx.x * 256 + threadIdx.x;
    int t = idx >> 7;
    int c = idx & 127;
    int s0 = slot_of[2 * t], s1 = slot_of[2 * t + 1];
    float w0 = top2w[2 * t], w1 = top2w[2 * t + 1];
    const short* e0 = eo;
    const short* e1 = eo + (size_t)NSLOT * DIM;
    s8v a0 = *(const s8v*)(e0 + (size_t)s0 * DIM + c * 8);
    s8v a1 = *(const s8v*)(e1 + (size_t)s0 * DIM + c * 8);
    s8v b0 = *(const s8v*)(e0 + (size_t)s1 * DIM + c * 8);
    s8v b1 = *(const s8v*)(e1 + (size_t)s1 * DIM + c * 8);
    float4 o[2];
#pragma unroll
    for (int j = 0; j < 8; ++j) {
        float v = w0 * (bf2f(a0[j]) + bf2f(a1[j])) + w1 * (bf2f(b0[j]) + bf2f(b1[j]));
        ((float*)o)[j] = v;
    }
    float4* op = (float4*)(out + (size_t)t * DIM + c * 8);
    op[0] = o[0];
    op[1] = o[1];
}

extern "C" void kernel_launch(void* const* d_in, const int* in_sizes, int n_in,
                              void* d_out, int out_size, void* d_ws, size_t ws_size,
                              hipStream_t stream) {
    const float* x    = (const float*)d_in[0];
    const float* gw   = (const float*)d_in[1];
    const float* bias = (const float*)d_in[2];
    const float* w1   = (const float*)d_in[3];
    const float* w2   = (const float*)d_in[4];
    float* out = (float*)d_out;

    char* ws = (char*)d_ws;
    short* xb  = (short*)ws;                          // 4 MiB  [T][DIM] bf16
    short* h   = (short*)(ws + (4ull << 20));         // 16 MiB [NSLOT][ED] bf16
    short* w1b = (short*)(ws + (20ull << 20));        // 32 MiB [NE][ED][DIM] bf16
    short* eo  = (short*)(ws + (20ull << 20));        // aliases w1b (ffn1 done before ffn2 writes)
    short* w2b = (short*)(ws + (52ull << 20));        // 32 MiB [NE][DIM][ED] bf16
    char* meta = ws + (84ull << 20);
    int*   counts   = (int*)(meta);                   // [8]
    int*   offsets  = (int*)(meta + 64);              // [8]
    int*   tok_list = (int*)(meta + 128);             // [NSLOT]
    int*   slot_of  = (int*)(meta + 128 + 4 * NSLOT); // [T*2]
    int*   top2i    = (int*)(meta + 128 + 8 * NSLOT); // [T*2]
    float* top2w    = (float*)(meta + 128 + 8 * NSLOT + 8 * T);
    int*   wl       = (int*)(meta + 128 + 8 * NSLOT + 16 * T);   // [MAXWL]
    int*   nwl      = (int*)(meta + 128 + 8 * NSLOT + 16 * T + 4 * MAXWL);

    hipMemsetAsync(counts, 0, 32, stream);

    prep_kernel<<<CONVB + T / 4, 256, 0, stream>>>(w1, w2, w1b, w2b,
                                                   x, gw, bias, xb, counts, top2i, top2w);
    plan_kernel<<<1, 256, 0, stream>>>(counts, top2i, offsets, tok_list, slot_of, wl, nwl);
    ffn1_kernel<<<dim3(ED / BN, MAXWL), 256, 0, stream>>>(xb, w1b, counts, offsets, tok_list, wl, nwl, h);
    ffn2_kernel<<<dim3(DIM / BN, MAXWL, KSPLIT), 256, 0, stream>>>(h, w2b, counts, offsets, wl, nwl, eo);
    combine_kernel<<<T * DIM / 8 / 256, 256, 0, stream>>>(eo, slot_of, top2w, out);
}

// Round 6
// 320.503 us; speedup vs baseline: 1.1518x; 1.1518x over previous
//
#include <hip/hip_runtime.h>

#define T 2048
#define DIM 1024
#define NE 8
#define ED 2048
#define NSLOT (T * 2)
#define KSPLIT 2

#define BM 128
#define BN 128
#define BK 32
#define MAXWL 40

typedef __attribute__((ext_vector_type(8))) short s8v;   // 8 bf16 = 4 VGPRs
typedef __attribute__((ext_vector_type(4))) float f32x4; // MFMA C/D

__device__ __forceinline__ short f2bf(float f) {
    union { float f; unsigned u; } v;
    v.f = f;
    unsigned r = 0x7FFFu + ((v.u >> 16) & 1u);  // round-to-nearest-even
    v.u += r;
    return (short)(v.u >> 16);
}

__device__ __forceinline__ float bf2f(short s) {
    union { unsigned u; float f; } v;
    v.u = ((unsigned)(unsigned short)s) << 16;
    return v.f;
}

// pack two fp32 -> two bf16 (round-half-up: add 0x8000, take high16) in 3 VALU
__device__ __forceinline__ unsigned pkbf2(float lo, float hi) {
    union { float f; unsigned u; } a, b;
    a.f = lo; b.f = hi;
    // result bytes: [0,1]=au[2,3], [2,3]=bu[2,3]; src0=high dword, src1=low dword
    return __builtin_amdgcn_perm(b.u + 0x8000u, a.u + 0x8000u, 0x07060302u);
}

// async global->LDS, 16B per lane; lds dst wave-uniform base, lane i -> base+16i
__device__ __forceinline__ void glds16(const void* g, void* l) {
    __builtin_amdgcn_global_load_lds(
        (const __attribute__((address_space(1))) void*)g,
        (__attribute__((address_space(3))) void*)l, 16, 0, 0);
}

// ---------------- router: 1 wave per token (also emits xb = bf16(x)) ----------------
__global__ void router_kernel(const float* __restrict__ x,
                              const float* __restrict__ gw,
                              const float* __restrict__ bias,
                              short* __restrict__ xb,
                              int* __restrict__ counts,
                              int* __restrict__ top2i,
                              float* __restrict__ top2w) {
    int wid = threadIdx.x >> 6;
    int lane = threadIdx.x & 63;
    int t = blockIdx.x * 4 + wid;

    const float* xr = x + (size_t)t * DIM + lane * 16;
    float4 xv[4];
#pragma unroll
    for (int j = 0; j < 4; ++j) xv[j] = *(const float4*)(xr + j * 4);

    s8v o0, o1;
#pragma unroll
    for (int j = 0; j < 2; ++j) {
        o0[j * 4 + 0] = f2bf(xv[j].x); o0[j * 4 + 1] = f2bf(xv[j].y);
        o0[j * 4 + 2] = f2bf(xv[j].z); o0[j * 4 + 3] = f2bf(xv[j].w);
        o1[j * 4 + 0] = f2bf(xv[j + 2].x); o1[j * 4 + 1] = f2bf(xv[j + 2].y);
        o1[j * 4 + 2] = f2bf(xv[j + 2].z); o1[j * 4 + 3] = f2bf(xv[j + 2].w);
    }
    *(s8v*)(xb + (size_t)t * DIM + lane * 16) = o0;
    *(s8v*)(xb + (size_t)t * DIM + lane * 16 + 8) = o1;

    float sc[NE];
#pragma unroll
    for (int e = 0; e < NE; ++e) {
        const float* gr = gw + e * DIM + lane * 16;
        float p = 0.f;
#pragma unroll
        for (int j = 0; j < 4; ++j) {
            float4 g = *(const float4*)(gr + j * 4);
            p += xv[j].x * g.x + xv[j].y * g.y + xv[j].z * g.z + xv[j].w * g.w;
        }
#pragma unroll
        for (int off = 32; off; off >>= 1) p += __shfl_xor(p, off, 64);
        sc[e] = 1.f / (1.f + __expf(-(p + bias[e])));
    }
    int b0 = 0; float s0 = sc[0];
#pragma unroll
    for (int e = 1; e < NE; ++e) if (sc[e] > s0) { s0 = sc[e]; b0 = e; }
    int b1 = -1; float s1 = -1e30f;
#pragma unroll
    for (int e = 0; e < NE; ++e) if (e != b0 && sc[e] > s1) { s1 = sc[e]; b1 = e; }
    float inv = 1.f / (s0 + s1 + 1e-6f);
    if (lane == 0) {
        top2i[t * 2 + 0] = b0; top2i[t * 2 + 1] = b1;
        top2w[t * 2 + 0] = s0 * inv; top2w[t * 2 + 1] = s1 * inv;
        atomicAdd(&counts[b0], 1);
        atomicAdd(&counts[b1], 1);
    }
}

// ---------------- plan: prefix + worklist + scatter ----------------
__global__ __launch_bounds__(256) void plan_kernel(
    const int* __restrict__ counts, const int* __restrict__ top2i,
    int* __restrict__ offsets, int* __restrict__ tok_list, int* __restrict__ slot_of,
    int* __restrict__ wl, int* __restrict__ nwl) {
    __shared__ int soff[NE];
    __shared__ int srun[NE];
    if (threadIdx.x == 0) {
        int a = 0;
        for (int e = 0; e < NE; ++e) { soff[e] = a; offsets[e] = a; a += counts[e]; srun[e] = 0; }
        int n = 0;
        for (int e = 0; e < NE; ++e) {
            int mt = (counts[e] + BM - 1) / BM;
            for (int m = 0; m < mt; ++m) wl[n++] = (e << 16) | m;
        }
        *nwl = n;
    }
    __syncthreads();
    for (int t = threadIdx.x; t < T; t += 256) {
#pragma unroll
        for (int k = 0; k < 2; ++k) {
            int e = top2i[t * 2 + k];
            int pos = atomicAdd(&srun[e], 1);
            int slot = soff[e] + pos;
            tok_list[slot] = t;
            slot_of[t * 2 + k] = slot;
        }
    }
}

// ---------------- grouped GEMM1: h = silu(x @ w1^T); A bf16 via glds, B fp32 inline-cvt ----------------
__global__ __launch_bounds__(256) void ffn1_kernel(
    const short* __restrict__ xb, const float* __restrict__ w1,
    const int* __restrict__ counts, const int* __restrict__ offsets,
    const int* __restrict__ tok_list, const int* __restrict__ wl,
    const int* __restrict__ nwl, short* __restrict__ h) {
    int my = blockIdx.y;
    if (my >= *nwl) return;
    int e = wl[my] >> 16;
    int m0 = (wl[my] & 0xffff) * BM;
    int cnt = counts[e];
    int off = offsets[e];
    int n0 = blockIdx.x * BN;

    __shared__ __align__(16) short As[2][4][BM][8];   // 16 KiB (dbuf, glds)
    __shared__ __align__(16) short Bs[4][BN][8];      // 8 KiB (single buf, ds_write)

    int tid = threadIdx.x;
    int lane = tid & 63, w = tid >> 6;
    int mo = (w >> 1) * 64, no = (w & 1) * 64;
    int lrow = lane & 15, lq = lane >> 4;

    f32x4 acc[4][4];
#pragma unroll
    for (int mi = 0; mi < 4; ++mi)
#pragma unroll
        for (int ni = 0; ni < 4; ++ni) acc[mi][ni] = (f32x4){0.f, 0.f, 0.f, 0.f};

    int ra0 = m0 + lane;      if (ra0 > cnt - 1) ra0 = cnt - 1;
    int ra1 = m0 + 64 + lane; if (ra1 > cnt - 1) ra1 = cnt - 1;
    const short* a0 = xb + (size_t)tok_list[off + ra0] * DIM + w * 8;
    const short* a1 = xb + (size_t)tok_list[off + ra1] * DIM + w * 8;

    // B staging: thread (br=tid>>1, bq=tid&1) loads 16 fp32 of row n0+br, k-half bq
    int br = tid >> 1, bq = tid & 1;
    const float* bp = w1 + ((size_t)e * ED + n0 + br) * DIM + bq * 16;

    const int NK = DIM / BK;   // 32
    float4 L0, L1, L2, L3;
    L0 = *(const float4*)(bp);     L1 = *(const float4*)(bp + 4);
    L2 = *(const float4*)(bp + 8); L3 = *(const float4*)(bp + 12);
    glds16(a0, &As[0][w][0][0]);
    glds16(a1, &As[0][w][64][0]);

    for (int kk = 0; kk < NK; ++kk) {
        int cur = kk & 1;
        __syncthreads();   // (1) drains prev-iter glds/loads (landed during compute) + prev LDS reads
        uint4 p0 = { pkbf2(L0.x, L0.y), pkbf2(L0.z, L0.w), pkbf2(L1.x, L1.y), pkbf2(L1.z, L1.w) };
        uint4 p1 = { pkbf2(L2.x, L2.y), pkbf2(L2.z, L2.w), pkbf2(L3.x, L3.y), pkbf2(L3.z, L3.w) };
        *(uint4*)&Bs[2 * bq][br][0] = p0;
        *(uint4*)&Bs[2 * bq + 1][br][0] = p1;
        __syncthreads();   // (2) B visible; no vmem issued since (1) -> cheap drain
        if (kk + 1 < NK) {
            int k0 = (kk + 1) * BK;
            glds16(a0 + k0, &As[cur ^ 1][w][0][0]);
            glds16(a1 + k0, &As[cur ^ 1][w][64][0]);
            const float* bpp = bp + k0;
            L0 = *(const float4*)(bpp);     L1 = *(const float4*)(bpp + 4);
            L2 = *(const float4*)(bpp + 8); L3 = *(const float4*)(bpp + 12);
        }
        s8v af[4], bf[4];
#pragma unroll
        for (int mi = 0; mi < 4; ++mi) af[mi] = *(const s8v*)&As[cur][lq][mo + mi * 16 + lrow][0];
#pragma unroll
        for (int ni = 0; ni < 4; ++ni) bf[ni] = *(const s8v*)&Bs[lq][no + ni * 16 + lrow][0];
#pragma unroll
        for (int mi = 0; mi < 4; ++mi)
#pragma unroll
            for (int ni = 0; ni < 4; ++ni)
                acc[mi][ni] = __builtin_amdgcn_mfma_f32_16x16x32_bf16(af[mi], bf[ni], acc[mi][ni], 0, 0, 0);
    }

#pragma unroll
    for (int mi = 0; mi < 4; ++mi) {
#pragma unroll
        for (int ni = 0; ni < 4; ++ni) {
            int ln = n0 + no + ni * 16 + lrow;
#pragma unroll
            for (int r = 0; r < 4; ++r) {
                int row = m0 + mo + mi * 16 + lq * 4 + r;
                if (row < cnt) {
                    float v = acc[mi][ni][r];
                    v = v / (1.f + __expf(-v));  // silu
                    h[(size_t)(off + row) * ED + ln] = f2bf(v);
                }
            }
        }
    }
}

// ---------------- grouped GEMM2 (K-split): eo[ks][slot] = h @ w2^T[kchunk]; B fp32 inline-cvt ----------------
__global__ __launch_bounds__(256) void ffn2_kernel(
    const short* __restrict__ h, const float* __restrict__ w2,
    const int* __restrict__ counts, const int* __restrict__ offsets,
    const int* __restrict__ wl, const int* __restrict__ nwl,
    short* __restrict__ eo) {
    int my = blockIdx.y;
    if (my >= *nwl) return;
    int e = wl[my] >> 16;
    int m0 = (wl[my] & 0xffff) * BM;
    int ksp = blockIdx.z;
    int cnt = counts[e];
    int off = offsets[e];
    int n0 = blockIdx.x * BN;
    const int kbase = ksp * (ED / KSPLIT);

    __shared__ __align__(16) short As[2][4][BM][8];
    __shared__ __align__(16) short Bs[4][BN][8];

    int tid = threadIdx.x;
    int lane = tid & 63, w = tid >> 6;
    int mo = (w >> 1) * 64, no = (w & 1) * 64;
    int lrow = lane & 15, lq = lane >> 4;

    f32x4 acc[4][4];
#pragma unroll
    for (int mi = 0; mi < 4; ++mi)
#pragma unroll
        for (int ni = 0; ni < 4; ++ni) acc[mi][ni] = (f32x4){0.f, 0.f, 0.f, 0.f};

    int ra0 = m0 + lane;      if (ra0 > cnt - 1) ra0 = cnt - 1;
    int ra1 = m0 + 64 + lane; if (ra1 > cnt - 1) ra1 = cnt - 1;
    const short* a0 = h + (size_t)(off + ra0) * ED + kbase + w * 8;
    const short* a1 = h + (size_t)(off + ra1) * ED + kbase + w * 8;

    int br = tid >> 1, bq = tid & 1;
    const float* bp = w2 + ((size_t)e * DIM + n0 + br) * ED + kbase + bq * 16;

    const int NK = (ED / KSPLIT) / BK;   // 32
    float4 L0, L1, L2, L3;
    L0 = *(const float4*)(bp);     L1 = *(const float4*)(bp + 4);
    L2 = *(const float4*)(bp + 8); L3 = *(const float4*)(bp + 12);
    glds16(a0, &As[0][w][0][0]);
    glds16(a1, &As[0][w][64][0]);

    for (int kk = 0; kk < NK; ++kk) {
        int cur = kk & 1;
        __syncthreads();
        uint4 p0 = { pkbf2(L0.x, L0.y), pkbf2(L0.z, L0.w), pkbf2(L1.x, L1.y), pkbf2(L1.z, L1.w) };
        uint4 p1 = { pkbf2(L2.x, L2.y), pkbf2(L2.z, L2.w), pkbf2(L3.x, L3.y), pkbf2(L3.z, L3.w) };
        *(uint4*)&Bs[2 * bq][br][0] = p0;
        *(uint4*)&Bs[2 * bq + 1][br][0] = p1;
        __syncthreads();
        if (kk + 1 < NK) {
            int k0 = (kk + 1) * BK;
            glds16(a0 + k0, &As[cur ^ 1][w][0][0]);
            glds16(a1 + k0, &As[cur ^ 1][w][64][0]);
            const float* bpp = bp + k0;
            L0 = *(const float4*)(bpp);     L1 = *(const float4*)(bpp + 4);
            L2 = *(const float4*)(bpp + 8); L3 = *(const float4*)(bpp + 12);
        }
        s8v af[4], bf[4];
#pragma unroll
        for (int mi = 0; mi < 4; ++mi) af[mi] = *(const s8v*)&As[cur][lq][mo + mi * 16 + lrow][0];
#pragma unroll
        for (int ni = 0; ni < 4; ++ni) bf[ni] = *(const s8v*)&Bs[lq][no + ni * 16 + lrow][0];
#pragma unroll
        for (int mi = 0; mi < 4; ++mi)
#pragma unroll
            for (int ni = 0; ni < 4; ++ni)
                acc[mi][ni] = __builtin_amdgcn_mfma_f32_16x16x32_bf16(af[mi], bf[ni], acc[mi][ni], 0, 0, 0);
    }

    short* eop = eo + (size_t)ksp * NSLOT * DIM;
#pragma unroll
    for (int mi = 0; mi < 4; ++mi) {
#pragma unroll
        for (int ni = 0; ni < 4; ++ni) {
            int ln = n0 + no + ni * 16 + lrow;
#pragma unroll
            for (int r = 0; r < 4; ++r) {
                int row = m0 + mo + mi * 16 + lq * 4 + r;
                if (row < cnt) {
                    eop[(size_t)(off + row) * DIM + ln] = f2bf(acc[mi][ni][r]);
                }
            }
        }
    }
}

// ---------------- combine ----------------
__global__ __launch_bounds__(256) void combine_kernel(
    const short* __restrict__ eo, const int* __restrict__ slot_of,
    const float* __restrict__ top2w, float* __restrict__ out) {
    int idx = blockIdx.x * 256 + threadIdx.x;
    int t = idx >> 7;
    int c = idx & 127;
    int s0 = slot_of[2 * t], s1 = slot_of[2 * t + 1];
    float w0 = top2w[2 * t], w1 = top2w[2 * t + 1];
    const short* e0 = eo;
    const short* e1 = eo + (size_t)NSLOT * DIM;
    s8v a0 = *(const s8v*)(e0 + (size_t)s0 * DIM + c * 8);
    s8v a1 = *(const s8v*)(e1 + (size_t)s0 * DIM + c * 8);
    s8v b0 = *(const s8v*)(e0 + (size_t)s1 * DIM + c * 8);
    s8v b1 = *(const s8v*)(e1 + (size_t)s1 * DIM + c * 8);
    float4 o[2];
#pragma unroll
    for (int j = 0; j < 8; ++j) {
        float v = w0 * (bf2f(a0[j]) + bf2f(a1[j])) + w1 * (bf2f(b0[j]) + bf2f(b1[j]));
        ((float*)o)[j] = v;
    }
    float4* op = (float4*)(out + (size_t)t * DIM + c * 8);
    op[0] = o[0];
    op[1] = o[1];
}

extern "C" void kernel_launch(void* const* d_in, const int* in_sizes, int n_in,
                              void* d_out, int out_size, void* d_ws, size_t ws_size,
                              hipStream_t stream) {
    const float* x    = (const float*)d_in[0];
    const float* gw   = (const float*)d_in[1];
    const float* bias = (const float*)d_in[2];
    const float* w1   = (const float*)d_in[3];
    const float* w2   = (const float*)d_in[4];
    float* out = (float*)d_out;

    char* ws = (char*)d_ws;
    short* xb = (short*)ws;                           // 4 MiB  [T][DIM] bf16
    short* h  = (short*)(ws + (4ull << 20));          // 16 MiB [NSLOT][ED] bf16
    short* eo = (short*)(ws + (20ull << 20));         // 16 MiB [2][NSLOT][DIM] bf16
    char* meta = ws + (36ull << 20);
    int*   counts   = (int*)(meta);                   // [8]
    int*   offsets  = (int*)(meta + 64);              // [8]
    int*   tok_list = (int*)(meta + 128);             // [NSLOT]
    int*   slot_of  = (int*)(meta + 128 + 4 * NSLOT); // [T*2]
    int*   top2i    = (int*)(meta + 128 + 8 * NSLOT); // [T*2]
    float* top2w    = (float*)(meta + 128 + 8 * NSLOT + 8 * T);
    int*   wl       = (int*)(meta + 128 + 8 * NSLOT + 16 * T);   // [MAXWL]
    int*   nwl      = (int*)(meta + 128 + 8 * NSLOT + 16 * T + 4 * MAXWL);

    hipMemsetAsync(counts, 0, 32, stream);

    router_kernel<<<T / 4, 256, 0, stream>>>(x, gw, bias, xb, counts, top2i, top2w);
    plan_kernel<<<1, 256, 0, stream>>>(counts, top2i, offsets, tok_list, slot_of, wl, nwl);
    ffn1_kernel<<<dim3(ED / BN, MAXWL), 256, 0, stream>>>(xb, w1, counts, offsets, tok_list, wl, nwl, h);
    ffn2_kernel<<<dim3(DIM / BN, MAXWL, KSPLIT), 256, 0, stream>>>(h, w2, counts, offsets, wl, nwl, eo);
    combine_kernel<<<T * DIM / 8 / 256, 256, 0, stream>>>(eo, slot_of, top2w, out);
}

// Round 7
// 316.998 us; speedup vs baseline: 1.1646x; 1.0111x over previous
//
#include <hip/hip_runtime.h>

#define T 2048
#define DIM 1024
#define NE 8
#define ED 2048
#define NSLOT (T * 2)
#define KSPLIT 2

#define BM 128
#define BN 128
#define BK 32
#define MAXWL 40

typedef __attribute__((ext_vector_type(8))) short s8v;   // 8 bf16 = 4 VGPRs
typedef __attribute__((ext_vector_type(4))) float f32x4; // MFMA C/D

__device__ __forceinline__ short f2bf(float f) {
    union { float f; unsigned u; } v;
    v.f = f;
    unsigned r = 0x7FFFu + ((v.u >> 16) & 1u);  // round-to-nearest-even
    v.u += r;
    return (short)(v.u >> 16);
}

__device__ __forceinline__ float bf2f(short s) {
    union { unsigned u; float f; } v;
    v.u = ((unsigned)(unsigned short)s) << 16;
    return v.f;
}

// pack two fp32 -> two bf16 (round-half-up) in 3 VALU: add 0x8000, perm high halves
__device__ __forceinline__ unsigned pkbf2(float lo, float hi) {
    union { float f; unsigned u; } a, b;
    a.f = lo; b.f = hi;
    return __builtin_amdgcn_perm(b.u + 0x8000u, a.u + 0x8000u, 0x07060302u);
}

// async global->LDS, 16B per lane; lds dst wave-uniform base, lane i -> base+16i
__device__ __forceinline__ void glds16(const void* g, void* l) {
    __builtin_amdgcn_global_load_lds(
        (const __attribute__((address_space(1))) void*)g,
        (__attribute__((address_space(3))) void*)l, 16, 0, 0);
}

// ---------------- router: 1 wave per token (also emits xb = bf16(x)) ----------------
__global__ void router_kernel(const float* __restrict__ x,
                              const float* __restrict__ gw,
                              const float* __restrict__ bias,
                              short* __restrict__ xb,
                              int* __restrict__ counts,
                              int* __restrict__ top2i,
                              float* __restrict__ top2w) {
    int wid = threadIdx.x >> 6;
    int lane = threadIdx.x & 63;
    int t = blockIdx.x * 4 + wid;

    const float* xr = x + (size_t)t * DIM + lane * 16;
    float4 xv[4];
#pragma unroll
    for (int j = 0; j < 4; ++j) xv[j] = *(const float4*)(xr + j * 4);

    s8v o0, o1;
#pragma unroll
    for (int j = 0; j < 2; ++j) {
        o0[j * 4 + 0] = f2bf(xv[j].x); o0[j * 4 + 1] = f2bf(xv[j].y);
        o0[j * 4 + 2] = f2bf(xv[j].z); o0[j * 4 + 3] = f2bf(xv[j].w);
        o1[j * 4 + 0] = f2bf(xv[j + 2].x); o1[j * 4 + 1] = f2bf(xv[j + 2].y);
        o1[j * 4 + 2] = f2bf(xv[j + 2].z); o1[j * 4 + 3] = f2bf(xv[j + 2].w);
    }
    *(s8v*)(xb + (size_t)t * DIM + lane * 16) = o0;
    *(s8v*)(xb + (size_t)t * DIM + lane * 16 + 8) = o1;

    float sc[NE];
#pragma unroll
    for (int e = 0; e < NE; ++e) {
        const float* gr = gw + e * DIM + lane * 16;
        float p = 0.f;
#pragma unroll
        for (int j = 0; j < 4; ++j) {
            float4 g = *(const float4*)(gr + j * 4);
            p += xv[j].x * g.x + xv[j].y * g.y + xv[j].z * g.z + xv[j].w * g.w;
        }
#pragma unroll
        for (int off = 32; off; off >>= 1) p += __shfl_xor(p, off, 64);
        sc[e] = 1.f / (1.f + __expf(-(p + bias[e])));
    }
    int b0 = 0; float s0 = sc[0];
#pragma unroll
    for (int e = 1; e < NE; ++e) if (sc[e] > s0) { s0 = sc[e]; b0 = e; }
    int b1 = -1; float s1 = -1e30f;
#pragma unroll
    for (int e = 0; e < NE; ++e) if (e != b0 && sc[e] > s1) { s1 = sc[e]; b1 = e; }
    float inv = 1.f / (s0 + s1 + 1e-6f);
    if (lane == 0) {
        top2i[t * 2 + 0] = b0; top2i[t * 2 + 1] = b1;
        top2w[t * 2 + 0] = s0 * inv; top2w[t * 2 + 1] = s1 * inv;
        atomicAdd(&counts[b0], 1);
        atomicAdd(&counts[b1], 1);
    }
}

// ---------------- plan: prefix + worklist + scatter ----------------
__global__ __launch_bounds__(256) void plan_kernel(
    const int* __restrict__ counts, const int* __restrict__ top2i,
    int* __restrict__ offsets, int* __restrict__ tok_list, int* __restrict__ slot_of,
    int* __restrict__ wl, int* __restrict__ nwl) {
    __shared__ int soff[NE];
    __shared__ int srun[NE];
    if (threadIdx.x == 0) {
        int a = 0;
        for (int e = 0; e < NE; ++e) { soff[e] = a; offsets[e] = a; a += counts[e]; srun[e] = 0; }
        int n = 0;
        for (int e = 0; e < NE; ++e) {
            int mt = (counts[e] + BM - 1) / BM;
            for (int m = 0; m < mt; ++m) wl[n++] = (e << 16) | m;
        }
        *nwl = n;
    }
    __syncthreads();
    for (int t = threadIdx.x; t < T; t += 256) {
#pragma unroll
        for (int k = 0; k < 2; ++k) {
            int e = top2i[t * 2 + k];
            int pos = atomicAdd(&srun[e], 1);
            int slot = soff[e] + pos;
            tok_list[slot] = t;
            slot_of[t * 2 + k] = slot;
        }
    }
}

// ---------------- grouped GEMM1: h = silu(x @ w1^T); single-barrier dbuf K-loop ----------------
__global__ __launch_bounds__(256) void ffn1_kernel(
    const short* __restrict__ xb, const float* __restrict__ w1,
    const int* __restrict__ counts, const int* __restrict__ offsets,
    const int* __restrict__ tok_list, const int* __restrict__ wl,
    const int* __restrict__ nwl, short* __restrict__ h) {
    int my = blockIdx.y;
    if (my >= *nwl) return;
    int e = wl[my] >> 16;
    int m0 = (wl[my] & 0xffff) * BM;
    int cnt = counts[e];
    int off = offsets[e];
    int n0 = blockIdx.x * BN;

    __shared__ __align__(16) short As[2][4][BM][8];   // 16 KiB (dbuf, glds)
    __shared__ __align__(16) short Bs[2][4][BN][8];   // 16 KiB (dbuf, ds_write)

    int tid = threadIdx.x;
    int lane = tid & 63, w = tid >> 6;
    int mo = (w >> 1) * 64, no = (w & 1) * 64;
    int lrow = lane & 15, lq = lane >> 4;

    f32x4 acc[4][4];
#pragma unroll
    for (int mi = 0; mi < 4; ++mi)
#pragma unroll
        for (int ni = 0; ni < 4; ++ni) acc[mi][ni] = (f32x4){0.f, 0.f, 0.f, 0.f};

    int ra0 = m0 + lane;      if (ra0 > cnt - 1) ra0 = cnt - 1;
    int ra1 = m0 + 64 + lane; if (ra1 > cnt - 1) ra1 = cnt - 1;
    const short* a0 = xb + (size_t)tok_list[off + ra0] * DIM + w * 8;
    const short* a1 = xb + (size_t)tok_list[off + ra1] * DIM + w * 8;

    // B staging: thread (br=tid>>1, bq=tid&1) loads 16 fp32 of row n0+br, k-half bq
    int br = tid >> 1, bq = tid & 1;
    const float* bp = w1 + ((size_t)e * ED + n0 + br) * DIM + bq * 16;

    const int NK = DIM / BK;   // 32
    float4 L0, L1, L2, L3;

    // ---- prologue: A(0)->As[0] async; B(0) -> regs -> Bs[0]; B(1) -> regs ----
    glds16(a0, &As[0][w][0][0]);
    glds16(a1, &As[0][w][64][0]);
    L0 = *(const float4*)(bp);     L1 = *(const float4*)(bp + 4);
    L2 = *(const float4*)(bp + 8); L3 = *(const float4*)(bp + 12);
    {
        uint4 p0 = { pkbf2(L0.x, L0.y), pkbf2(L0.z, L0.w), pkbf2(L1.x, L1.y), pkbf2(L1.z, L1.w) };
        uint4 p1 = { pkbf2(L2.x, L2.y), pkbf2(L2.z, L2.w), pkbf2(L3.x, L3.y), pkbf2(L3.z, L3.w) };
        *(uint4*)&Bs[0][2 * bq][br][0] = p0;
        *(uint4*)&Bs[0][2 * bq + 1][br][0] = p1;
    }
    L0 = *(const float4*)(bp + BK);     L1 = *(const float4*)(bp + BK + 4);
    L2 = *(const float4*)(bp + BK + 8); L3 = *(const float4*)(bp + BK + 12);

    for (int kk = 0; kk < NK; ++kk) {
        int cur = kk & 1, nxt = cur ^ 1;
        __syncthreads();   // single barrier: all prior glds/loads/ds_writes landed & visible
        if (kk + 1 < NK) {
            int k0 = (kk + 1) * BK;
            glds16(a0 + k0, &As[nxt][w][0][0]);
            glds16(a1 + k0, &As[nxt][w][64][0]);
            // L-regs hold B(kk+1), force-landed by the barrier: pack stalls never
            uint4 p0 = { pkbf2(L0.x, L0.y), pkbf2(L0.z, L0.w), pkbf2(L1.x, L1.y), pkbf2(L1.z, L1.w) };
            uint4 p1 = { pkbf2(L2.x, L2.y), pkbf2(L2.z, L2.w), pkbf2(L3.x, L3.y), pkbf2(L3.z, L3.w) };
            *(uint4*)&Bs[nxt][2 * bq][br][0] = p0;
            *(uint4*)&Bs[nxt][2 * bq + 1][br][0] = p1;
            if (kk + 2 < NK) {
                const float* bpp = bp + (kk + 2) * BK;
                L0 = *(const float4*)(bpp);     L1 = *(const float4*)(bpp + 4);
                L2 = *(const float4*)(bpp + 8); L3 = *(const float4*)(bpp + 12);
            }
        }
        s8v af[4], bf[4];
#pragma unroll
        for (int mi = 0; mi < 4; ++mi) af[mi] = *(const s8v*)&As[cur][lq][mo + mi * 16 + lrow][0];
#pragma unroll
        for (int ni = 0; ni < 4; ++ni) bf[ni] = *(const s8v*)&Bs[cur][lq][no + ni * 16 + lrow][0];
#pragma unroll
        for (int mi = 0; mi < 4; ++mi)
#pragma unroll
            for (int ni = 0; ni < 4; ++ni)
                acc[mi][ni] = __builtin_amdgcn_mfma_f32_16x16x32_bf16(af[mi], bf[ni], acc[mi][ni], 0, 0, 0);
    }

#pragma unroll
    for (int mi = 0; mi < 4; ++mi) {
#pragma unroll
        for (int ni = 0; ni < 4; ++ni) {
            int ln = n0 + no + ni * 16 + lrow;
#pragma unroll
            for (int r = 0; r < 4; ++r) {
                int row = m0 + mo + mi * 16 + lq * 4 + r;
                if (row < cnt) {
                    float v = acc[mi][ni][r];
                    v = v / (1.f + __expf(-v));  // silu
                    h[(size_t)(off + row) * ED + ln] = f2bf(v);
                }
            }
        }
    }
}

// ---------------- grouped GEMM2 (K-split): eo[ks][slot] = h @ w2^T[kchunk]; same pipeline ----------------
__global__ __launch_bounds__(256) void ffn2_kernel(
    const short* __restrict__ h, const float* __restrict__ w2,
    const int* __restrict__ counts, const int* __restrict__ offsets,
    const int* __restrict__ wl, const int* __restrict__ nwl,
    short* __restrict__ eo) {
    int my = blockIdx.y;
    if (my >= *nwl) return;
    int e = wl[my] >> 16;
    int m0 = (wl[my] & 0xffff) * BM;
    int ksp = blockIdx.z;
    int cnt = counts[e];
    int off = offsets[e];
    int n0 = blockIdx.x * BN;
    const int kbase = ksp * (ED / KSPLIT);

    __shared__ __align__(16) short As[2][4][BM][8];
    __shared__ __align__(16) short Bs[2][4][BN][8];

    int tid = threadIdx.x;
    int lane = tid & 63, w = tid >> 6;
    int mo = (w >> 1) * 64, no = (w & 1) * 64;
    int lrow = lane & 15, lq = lane >> 4;

    f32x4 acc[4][4];
#pragma unroll
    for (int mi = 0; mi < 4; ++mi)
#pragma unroll
        for (int ni = 0; ni < 4; ++ni) acc[mi][ni] = (f32x4){0.f, 0.f, 0.f, 0.f};

    int ra0 = m0 + lane;      if (ra0 > cnt - 1) ra0 = cnt - 1;
    int ra1 = m0 + 64 + lane; if (ra1 > cnt - 1) ra1 = cnt - 1;
    const short* a0 = h + (size_t)(off + ra0) * ED + kbase + w * 8;
    const short* a1 = h + (size_t)(off + ra1) * ED + kbase + w * 8;

    int br = tid >> 1, bq = tid & 1;
    const float* bp = w2 + ((size_t)e * DIM + n0 + br) * ED + kbase + bq * 16;

    const int NK = (ED / KSPLIT) / BK;   // 32
    float4 L0, L1, L2, L3;

    glds16(a0, &As[0][w][0][0]);
    glds16(a1, &As[0][w][64][0]);
    L0 = *(const float4*)(bp);     L1 = *(const float4*)(bp + 4);
    L2 = *(const float4*)(bp + 8); L3 = *(const float4*)(bp + 12);
    {
        uint4 p0 = { pkbf2(L0.x, L0.y), pkbf2(L0.z, L0.w), pkbf2(L1.x, L1.y), pkbf2(L1.z, L1.w) };
        uint4 p1 = { pkbf2(L2.x, L2.y), pkbf2(L2.z, L2.w), pkbf2(L3.x, L3.y), pkbf2(L3.z, L3.w) };
        *(uint4*)&Bs[0][2 * bq][br][0] = p0;
        *(uint4*)&Bs[0][2 * bq + 1][br][0] = p1;
    }
    L0 = *(const float4*)(bp + BK);     L1 = *(const float4*)(bp + BK + 4);
    L2 = *(const float4*)(bp + BK + 8); L3 = *(const float4*)(bp + BK + 12);

    for (int kk = 0; kk < NK; ++kk) {
        int cur = kk & 1, nxt = cur ^ 1;
        __syncthreads();
        if (kk + 1 < NK) {
            int k0 = (kk + 1) * BK;
            glds16(a0 + k0, &As[nxt][w][0][0]);
            glds16(a1 + k0, &As[nxt][w][64][0]);
            uint4 p0 = { pkbf2(L0.x, L0.y), pkbf2(L0.z, L0.w), pkbf2(L1.x, L1.y), pkbf2(L1.z, L1.w) };
            uint4 p1 = { pkbf2(L2.x, L2.y), pkbf2(L2.z, L2.w), pkbf2(L3.x, L3.y), pkbf2(L3.z, L3.w) };
            *(uint4*)&Bs[nxt][2 * bq][br][0] = p0;
            *(uint4*)&Bs[nxt][2 * bq + 1][br][0] = p1;
            if (kk + 2 < NK) {
                const float* bpp = bp + (kk + 2) * BK;
                L0 = *(const float4*)(bpp);     L1 = *(const float4*)(bpp + 4);
                L2 = *(const float4*)(bpp + 8); L3 = *(const float4*)(bpp + 12);
            }
        }
        s8v af[4], bf[4];
#pragma unroll
        for (int mi = 0; mi < 4; ++mi) af[mi] = *(const s8v*)&As[cur][lq][mo + mi * 16 + lrow][0];
#pragma unroll
        for (int ni = 0; ni < 4; ++ni) bf[ni] = *(const s8v*)&Bs[cur][lq][no + ni * 16 + lrow][0];
#pragma unroll
        for (int mi = 0; mi < 4; ++mi)
#pragma unroll
            for (int ni = 0; ni < 4; ++ni)
                acc[mi][ni] = __builtin_amdgcn_mfma_f32_16x16x32_bf16(af[mi], bf[ni], acc[mi][ni], 0, 0, 0);
    }

    short* eop = eo + (size_t)ksp * NSLOT * DIM;
#pragma unroll
    for (int mi = 0; mi < 4; ++mi) {
#pragma unroll
        for (int ni = 0; ni < 4; ++ni) {
            int ln = n0 + no + ni * 16 + lrow;
#pragma unroll
            for (int r = 0; r < 4; ++r) {
                int row = m0 + mo + mi * 16 + lq * 4 + r;
                if (row < cnt) {
                    eop[(size_t)(off + row) * DIM + ln] = f2bf(acc[mi][ni][r]);
                }
            }
        }
    }
}

// ---------------- combine ----------------
__global__ __launch_bounds__(256) void combine_kernel(
    const short* __restrict__ eo, const int* __restrict__ slot_of,
    const float* __restrict__ top2w, float* __restrict__ out) {
    int idx = blockIdx.x * 256 + threadIdx.x;
    int t = idx >> 7;
    int c = idx & 127;
    int s0 = slot_of[2 * t], s1 = slot_of[2 * t + 1];
    float w0 = top2w[2 * t], w1 = top2w[2 * t + 1];
    const short* e0 = eo;
    const short* e1 = eo + (size_t)NSLOT * DIM;
    s8v a0 = *(const s8v*)(e0 + (size_t)s0 * DIM + c * 8);
    s8v a1 = *(const s8v*)(e1 + (size_t)s0 * DIM + c * 8);
    s8v b0 = *(const s8v*)(e0 + (size_t)s1 * DIM + c * 8);
    s8v b1 = *(const s8v*)(e1 + (size_t)s1 * DIM + c * 8);
    float4 o[2];
#pragma unroll
    for (int j = 0; j < 8; ++j) {
        float v = w0 * (bf2f(a0[j]) + bf2f(a1[j])) + w1 * (bf2f(b0[j]) + bf2f(b1[j]));
        ((float*)o)[j] = v;
    }
    float4* op = (float4*)(out + (size_t)t * DIM + c * 8);
    op[0] = o[0];
    op[1] = o[1];
}

extern "C" void kernel_launch(void* const* d_in, const int* in_sizes, int n_in,
                              void* d_out, int out_size, void* d_ws, size_t ws_size,
                              hipStream_t stream) {
    const float* x    = (const float*)d_in[0];
    const float* gw   = (const float*)d_in[1];
    const float* bias = (const float*)d_in[2];
    const float* w1   = (const float*)d_in[3];
    const float* w2   = (const float*)d_in[4];
    float* out = (float*)d_out;

    char* ws = (char*)d_ws;
    short* xb = (short*)ws;                           // 4 MiB  [T][DIM] bf16
    short* h  = (short*)(ws + (4ull << 20));          // 16 MiB [NSLOT][ED] bf16
    short* eo = (short*)(ws + (20ull << 20));         // 16 MiB [2][NSLOT][DIM] bf16
    char* meta = ws + (36ull << 20);
    int*   counts   = (int*)(meta);                   // [8]
    int*   offsets  = (int*)(meta + 64);              // [8]
    int*   tok_list = (int*)(meta + 128);             // [NSLOT]
    int*   slot_of  = (int*)(meta + 128 + 4 * NSLOT); // [T*2]
    int*   top2i    = (int*)(meta + 128 + 8 * NSLOT); // [T*2]
    float* top2w    = (float*)(meta + 128 + 8 * NSLOT + 8 * T);
    int*   wl       = (int*)(meta + 128 + 8 * NSLOT + 16 * T);   // [MAXWL]
    int*   nwl      = (int*)(meta + 128 + 8 * NSLOT + 16 * T + 4 * MAXWL);

    hipMemsetAsync(counts, 0, 32, stream);

    router_kernel<<<T / 4, 256, 0, stream>>>(x, gw, bias, xb, counts, top2i, top2w);
    plan_kernel<<<1, 256, 0, stream>>>(counts, top2i, offsets, tok_list, slot_of, wl, nwl);
    ffn1_kernel<<<dim3(ED / BN, MAXWL), 256, 0, stream>>>(xb, w1, counts, offsets, tok_list, wl, nwl, h);
    ffn2_kernel<<<dim3(DIM / BN, MAXWL, KSPLIT), 256, 0, stream>>>(h, w2, counts, offsets, wl, nwl, eo);
    combine_kernel<<<T * DIM / 8 / 256, 256, 0, stream>>>(eo, slot_of, top2w, out);
}